// Round 4
// baseline (369.001 us; speedup 1.0000x reference)
//
#include <hip/hip_runtime.h>
#include <math.h>

// Problem constants (setup_inputs): B=4, N=2048, C=512, H=8, Dh=64
#define BB 4
#define NN 2048
#define CC 512
#define HH 8
#define DH 64
#define MM (BB*NN)          // 8192 rows
#define QKV_N (3*CC)        // 1536

typedef _Float16 f16;
typedef __attribute__((ext_vector_type(4))) _Float16 f16x4;
typedef __attribute__((ext_vector_type(8))) _Float16 f16x8;
typedef __attribute__((ext_vector_type(4))) float f32x4;

#define L2E 1.4426950408889634f

// async global->LDS, 16B per lane. LDS dest is wave-uniform base + lane*16,
// so LDS layout MUST be exact lane-order (no padding).
#define GL16(g, l) __builtin_amdgcn_global_load_lds(                       \
    (const __attribute__((address_space(1))) void*)(g),                    \
    (__attribute__((address_space(3))) void*)(l), 16, 0, 0)

// ---------------------------------------------------------------------------
// Kernel 0: cast x, Wqkv, Wproj to fp16 (vectorized, memory-bound).
// ---------------------------------------------------------------------------
#define SX4 (MM*CC/4)          // 1048576
#define SW4 (QKV_N*CC/4)       // 196608
#define SP4 (CC*CC/4)          // 65536
__global__ __launch_bounds__(256) void cast_kernel(
    const float* __restrict__ x, const float* __restrict__ wqkv,
    const float* __restrict__ wproj,
    f16* __restrict__ xh, f16* __restrict__ wqh, f16* __restrict__ wph)
{
    const int t = blockIdx.x * 256 + threadIdx.x;
    const float* src; f16* dst; int i;
    if (t < SX4)            { src = x;     dst = xh;  i = t; }
    else if (t < SX4 + SW4) { src = wqkv;  dst = wqh; i = t - SX4; }
    else                    { src = wproj; dst = wph; i = t - SX4 - SW4; }
    f32x4 v = *(const f32x4*)(src + 4 * (size_t)i);
    f16x4 h = { (f16)v[0], (f16)v[1], (f16)v[2], (f16)v[3] };
    *(f16x4*)(dst + 4 * (size_t)i) = h;
}

// ---------------------------------------------------------------------------
// Kernel 1: QKV GEMM, fp16 MFMA. M=8192, N=1536, K=512. 128x128 tile, BK=32.
// Epilogue: q,k -> (B,H,N,Dh) fp16 ; v -> transposed (B,H,Dh,N) fp16.
// ---------------------------------------------------------------------------
__global__ __launch_bounds__(256) void qkv_gemm(
    const f16* __restrict__ xh, const f16* __restrict__ wh,
    f16* __restrict__ qo, f16* __restrict__ ko, f16* __restrict__ vto)
{
    __shared__ f16 As[128][32];
    __shared__ f16 Bs[128][32];
    const int m0 = blockIdx.x * 128;
    const int n0 = blockIdx.y * 128;
    const int tid = threadIdx.x;
    const int lane = tid & 63;
    const int w = tid >> 6;
    const int wm = (w & 1) * 64, wn = (w >> 1) * 64;
    const int l15 = lane & 15, quad = lane >> 4;

    const int sr = tid >> 2;           // staging row 0..63
    const int sc = (tid & 3) * 8;      // staging col (halves)
    const f16* ga0 = xh + (size_t)(m0 + sr) * CC + sc;
    const f16* ga1 = xh + (size_t)(m0 + sr + 64) * CC + sc;
    const f16* gb0 = wh + (size_t)(n0 + sr) * CC + sc;
    const f16* gb1 = wh + (size_t)(n0 + sr + 64) * CC + sc;
    f16* la0 = &As[sr][sc];      f16* la1 = &As[sr + 64][sc];
    f16* lb0 = &Bs[sr][sc];      f16* lb1 = &Bs[sr + 64][sc];

    f32x4 acc[4][4] = {};
    for (int k0 = 0; k0 < CC; k0 += 32) {
        __syncthreads();
        GL16(ga0 + k0, la0);
        GL16(ga1 + k0, la1);
        GL16(gb0 + k0, lb0);
        GL16(gb1 + k0, lb1);
        __syncthreads();

        f16x8 af[4], bf[4];
        #pragma unroll
        for (int mi = 0; mi < 4; ++mi)
            af[mi] = *(const f16x8*)&As[wm + mi*16 + l15][quad * 8];
        #pragma unroll
        for (int ni = 0; ni < 4; ++ni)
            bf[ni] = *(const f16x8*)&Bs[wn + ni*16 + l15][quad * 8];
        #pragma unroll
        for (int mi = 0; mi < 4; ++mi)
            #pragma unroll
            for (int ni = 0; ni < 4; ++ni)
                acc[mi][ni] = __builtin_amdgcn_mfma_f32_16x16x32_f16(
                    af[mi], bf[ni], acc[mi][ni], 0, 0, 0);
    }

    const int which = n0 >> 9;          // 0=q, 1=k, 2=v
    const int b     = m0 >> 11;
    const int mloc  = m0 & (NN - 1);

    if (which == 2) {
        #pragma unroll
        for (int mi = 0; mi < 4; ++mi)
            #pragma unroll
            for (int ni = 0; ni < 4; ++ni) {
                const int cl = wn + ni*16 + l15;
                const int hh = ((n0 & 511) + cl) >> 6;
                const int d  = ((n0 & 511) + cl) & 63;
                const int n  = mloc + wm + mi*16 + quad*4;
                f16x4 pk = { (f16)acc[mi][ni][0], (f16)acc[mi][ni][1],
                             (f16)acc[mi][ni][2], (f16)acc[mi][ni][3] };
                *(f16x4*)(vto + ((size_t)(b*HH + hh) * DH + d) * NN + n) = pk;
            }
        return;
    }

    f16* dst = which ? ko : qo;
    #pragma unroll
    for (int mi = 0; mi < 4; ++mi)
        #pragma unroll
        for (int r = 0; r < 4; ++r) {
            const int n = mloc + wm + mi*16 + quad*4 + r;
            #pragma unroll
            for (int ni = 0; ni < 4; ++ni) {
                const int cl = wn + ni*16 + l15;
                const int hh = ((n0 & 511) + cl) >> 6;
                const int d  = ((n0 & 511) + cl) & 63;
                dst[((size_t)(b*HH + hh) * NN + n) * DH + d] = (f16)acc[mi][ni][r];
            }
        }
}

// ---------------------------------------------------------------------------
// Kernel 2: RoPE over q,k in place (B,H,N,Dh). Fully in-lane.
// ---------------------------------------------------------------------------
__global__ __launch_bounds__(256) void rope_kernel(
    f16* __restrict__ q, f16* __restrict__ k,
    const float* __restrict__ times, const int* __restrict__ nclsp)
{
    const int t = blockIdx.x * 256 + threadIdx.x;    // 0 .. 524287
    const int row = t >> 3;                          // bh*2048 + n
    const int d0  = (t & 7) * 8;
    const int n   = row & (NN - 1);
    const int b   = row >> 14;                       // /(H*N)
    if (n < *nclsp) return;
    const float pos = rintf(times[b * NN + n] * 30.0f);   // MAX_FPS

    f16x8 qv = *(const f16x8*)(q + (size_t)row * DH + d0);
    f16x8 kv = *(const f16x8*)(k + (size_t)row * DH + d0);
    f16x8 qr, kr;
    #pragma unroll
    for (int p = 0; p < 4; ++p) {
        const int j = (d0 >> 1) + p;
        const float invf = exp2f((float)j * (-13.287712379549449f / 32.0f));
        float s, c;
        sincosf(pos * invf, &s, &c);
        const float q0 = (float)qv[2*p], q1 = (float)qv[2*p+1];
        qr[2*p]   = (f16)(q0 * c - q1 * s);
        qr[2*p+1] = (f16)(q0 * s + q1 * c);
        const float k0 = (float)kv[2*p], k1 = (float)kv[2*p+1];
        kr[2*p]   = (f16)(k0 * c - k1 * s);
        kr[2*p+1] = (f16)(k0 * s + k1 * c);
    }
    *(f16x8*)(q + (size_t)row * DH + d0) = qr;
    *(f16x8*)(k + (size_t)row * DH + d0) = kr;
}

// ---------------------------------------------------------------------------
// Kernel 3: fp16-MFMA flash attention, KV-split within block.
// Grid (32 bh, 16 qt); block 512 = 8 waves. Wave w: q rows [qt*128+(w&3)*32),
// keys half (w>>2). Pairwise merge (w, w+4) through LDS at the end.
// LDS pads: 66 halves (33 dwords = 1 mod 32 -> ~2-way), Pt 34 halves.
// ---------------------------------------------------------------------------
__global__ __launch_bounds__(512, 4) void attn_kernel(
    const f16* __restrict__ qg, const f16* __restrict__ kg,
    const f16* __restrict__ vtg, const float* __restrict__ mask,
    f16* __restrict__ out)
{
    __shared__ __align__(16) char smem[51712];
    f16 (*Kh)[64][66]   = (f16 (*)[64][66])smem;              // [kvh][key][d]
    f16 (*Vt)[64][66]   = (f16 (*)[64][66])(smem + 16896);    // [kvh][d][key]
    f16 (*Pt)[32][34]   = (f16 (*)[32][34])(smem + 33792);    // [wave][q][key32]
    float (*Msk)[64]    = (float (*)[64])(smem + 51200);      // [kvh][key]
    // merge overlay (after final barrier):
    float (*Om)[32][66] = (float (*)[32][66])smem;            // [qw][q][d]
    float2 (*Ml)[2][16] = (float2 (*)[2][16])(smem + 33792);  // [qw][ni][l15]

    const int bh = blockIdx.x, qt = blockIdx.y;
    const int b = bh >> 3, h = bh & 7;
    const int tid = threadIdx.x;
    const int w = tid >> 6, lane = tid & 63;
    const int l15 = lane & 15, quad = lane >> 4;
    const int qw = w & 3, kvh = w >> 2;

    const f16* qbase  = qg  + ((size_t)bh * NN + qt*128 + qw*32) * DH;
    const float* mbase = mask + (size_t)b * NN;

    // Q B-fragments, persistent: q = 16ni+l15, k(d) = kc*32 + quad*8..+8
    f16x8 Bq[2][2];
    #pragma unroll
    for (int ni = 0; ni < 2; ++ni)
        #pragma unroll
        for (int kc = 0; kc < 2; ++kc)
            Bq[ni][kc] = *(const f16x8*)(qbase + (size_t)(16*ni + l15) * DH
                                         + kc*32 + quad*8);

    f32x4 O[2][4] = {};                   // [q-block mi2][d-block nd]
    float m_run[2] = { -INFINITY, -INFINITY };
    float l_run[2] = { 0.0f, 0.0f };
    const float scl = 0.125f * L2E;

    const int sr = tid >> 3;              // 0..63
    const int scol = (tid & 7) * 8;

    for (int kt = 0; kt < 16; ++kt) {
        __syncthreads();                  // prior-iter Kh/Vt/Msk reads done
        // Cooperative staging of both KV halves (64 keys each).
        *(f16x8*)&Kh[0][sr][scol] =
            *(const f16x8*)(kg + ((size_t)bh*NN + kt*64 + sr) * DH + scol);
        *(f16x8*)&Kh[1][sr][scol] =
            *(const f16x8*)(kg + ((size_t)bh*NN + 1024 + kt*64 + sr) * DH + scol);
        *(f16x8*)&Vt[0][sr][scol] =
            *(const f16x8*)(vtg + (size_t)bh*DH*NN + (size_t)sr*NN + kt*64 + scol);
        *(f16x8*)&Vt[1][sr][scol] =
            *(const f16x8*)(vtg + (size_t)bh*DH*NN + (size_t)sr*NN + 1024 + kt*64 + scol);
        if (tid < 32) {
            const int kv2 = tid >> 4, off = (tid & 15) * 4;
            f32x4 mv = *(const f32x4*)(mbase + kv2*1024 + kt*64 + off);
            mv *= L2E;
            *(f32x4*)&Msk[kv2][off] = mv;
        }
        __syncthreads();

        // S^T = K · Q^T : st[mi over 16-key blocks][ni over 16-q blocks]
        f32x4 st[4][2] = {};
        #pragma unroll
        for (int mi = 0; mi < 4; ++mi) {
            f16x8 Ak0 = *(const f16x8*)&Kh[kvh][16*mi + l15][quad*8];
            f16x8 Ak1 = *(const f16x8*)&Kh[kvh][16*mi + l15][32 + quad*8];
            #pragma unroll
            for (int ni = 0; ni < 2; ++ni) {
                st[mi][ni] = __builtin_amdgcn_mfma_f32_16x16x32_f16(Ak0, Bq[ni][0], st[mi][ni], 0, 0, 0);
                st[mi][ni] = __builtin_amdgcn_mfma_f32_16x16x32_f16(Ak1, Bq[ni][1], st[mi][ni], 0, 0, 0);
            }
        }

        f32x4 mskv[4];
        #pragma unroll
        for (int mi = 0; mi < 4; ++mi)
            mskv[mi] = *(const f32x4*)&Msk[kvh][16*mi + quad*4];

        float alpha[2];
        bool upd = false;
        f16x4 ph[4][2];
        #pragma unroll
        for (int ni = 0; ni < 2; ++ni) {
            float mloc = -INFINITY;
            #pragma unroll
            for (int mi = 0; mi < 4; ++mi)
                #pragma unroll
                for (int r = 0; r < 4; ++r) {
                    float s2 = st[mi][ni][r] * scl + mskv[mi][r];
                    st[mi][ni][r] = s2;
                    mloc = fmaxf(mloc, s2);
                }
            mloc = fmaxf(mloc, __shfl_xor(mloc, 16));
            mloc = fmaxf(mloc, __shfl_xor(mloc, 32));
            const float mnew = fmaxf(m_run[ni], mloc);
            upd |= (mnew > m_run[ni]);
            alpha[ni] = exp2f(m_run[ni] - mnew);
            m_run[ni] = mnew;
            float rs = 0.0f;
            #pragma unroll
            for (int mi = 0; mi < 4; ++mi)
                #pragma unroll
                for (int r = 0; r < 4; ++r) {
                    float p = exp2f(st[mi][ni][r] - mnew);
                    rs += p;
                    ph[mi][ni][r] = (f16)p;
                }
            rs += __shfl_xor(rs, 16);
            rs += __shfl_xor(rs, 32);
            l_run[ni] = l_run[ni] * alpha[ni] + rs;
        }

        // Rescale O only when some row's max moved (wave-uniform branch).
        if (__any((int)upd)) {
            #pragma unroll
            for (int mi2 = 0; mi2 < 2; ++mi2) {
                f32x4 av;
                #pragma unroll
                for (int r = 0; r < 4; ++r)
                    av[r] = __shfl(alpha[mi2], quad*4 + r);
                #pragma unroll
                for (int nd = 0; nd < 4; ++nd)
                    O[mi2][nd] *= av;
            }
        }

        // O += P · V in two 32-key passes through the small Pt buffer.
        #pragma unroll
        for (int s = 0; s < 2; ++s) {
            #pragma unroll
            for (int ni = 0; ni < 2; ++ni)
                #pragma unroll
                for (int m = 0; m < 2; ++m)
                    *(f16x4*)&Pt[w][16*ni + l15][m*16 + quad*4] = ph[2*s + m][ni];
            f16x8 Ap0 = *(const f16x8*)&Pt[w][l15][quad*8];
            f16x8 Ap1 = *(const f16x8*)&Pt[w][16 + l15][quad*8];
            #pragma unroll
            for (int nd = 0; nd < 4; ++nd) {
                f16x8 Bv = *(const f16x8*)&Vt[kvh][16*nd + l15][s*32 + quad*8];
                O[0][nd] = __builtin_amdgcn_mfma_f32_16x16x32_f16(Ap0, Bv, O[0][nd], 0, 0, 0);
                O[1][nd] = __builtin_amdgcn_mfma_f32_16x16x32_f16(Ap1, Bv, O[1][nd], 0, 0, 0);
            }
        }
    }

    // ---- merge the two KV halves (wave w<4 with partner w+4) ----
    __syncthreads();
    if (w >= 4) {
        const int pw = w - 4;
        #pragma unroll
        for (int mi2 = 0; mi2 < 2; ++mi2)
            #pragma unroll
            for (int nd = 0; nd < 4; ++nd)
                #pragma unroll
                for (int r = 0; r < 4; ++r)
                    Om[pw][16*mi2 + quad*4 + r][16*nd + l15] = O[mi2][nd][r];
        if (quad == 0) {
            Ml[pw][0][l15] = make_float2(m_run[0], l_run[0]);
            Ml[pw][1][l15] = make_float2(m_run[1], l_run[1]);
        }
    }
    __syncthreads();
    if (w < 4) {
        float s0[2], s1[2];
        #pragma unroll
        for (int ni = 0; ni < 2; ++ni) {
            float2 t = Ml[w][ni][l15];
            float M  = fmaxf(m_run[ni], t.x);
            float a0 = exp2f(m_run[ni] - M);
            float a1 = exp2f(t.x - M);
            float L  = a0 * l_run[ni] + a1 * t.y;
            float inv = 1.0f / L;
            s0[ni] = a0 * inv;
            s1[ni] = a1 * inv;
        }
        #pragma unroll
        for (int mi2 = 0; mi2 < 2; ++mi2) {
            f32x4 f0, f1;
            #pragma unroll
            for (int r = 0; r < 4; ++r) {
                f0[r] = __shfl(s0[mi2], quad*4 + r);
                f1[r] = __shfl(s1[mi2], quad*4 + r);
            }
            #pragma unroll
            for (int nd = 0; nd < 4; ++nd)
                #pragma unroll
                for (int r = 0; r < 4; ++r) {
                    const int q = qt*128 + w*32 + 16*mi2 + quad*4 + r;
                    float o = O[mi2][nd][r] * f0[r]
                            + Om[w][16*mi2 + quad*4 + r][16*nd + l15] * f1[r];
                    out[((size_t)b * NN + q) * CC + h*DH + 16*nd + l15] = (f16)o;
                }
        }
    }
}

// ---------------------------------------------------------------------------
// Kernel 4: proj GEMM, fp16 MFMA. M=8192, N=512, K=512. fp32 out + bias.
// ---------------------------------------------------------------------------
__global__ __launch_bounds__(256) void proj_gemm(
    const f16* __restrict__ ah, const f16* __restrict__ wh,
    const float* __restrict__ bias, float* __restrict__ out)
{
    __shared__ f16 As[128][32];
    __shared__ f16 Bs[128][32];
    const int m0 = blockIdx.x * 128;
    const int n0 = blockIdx.y * 128;
    const int tid = threadIdx.x;
    const int lane = tid & 63;
    const int w = tid >> 6;
    const int wm = (w & 1) * 64, wn = (w >> 1) * 64;
    const int l15 = lane & 15, quad = lane >> 4;

    const int sr = tid >> 2;
    const int sc = (tid & 3) * 8;
    const f16* ga0 = ah + (size_t)(m0 + sr) * CC + sc;
    const f16* ga1 = ah + (size_t)(m0 + sr + 64) * CC + sc;
    const f16* gb0 = wh + (size_t)(n0 + sr) * CC + sc;
    const f16* gb1 = wh + (size_t)(n0 + sr + 64) * CC + sc;
    f16* la0 = &As[sr][sc];      f16* la1 = &As[sr + 64][sc];
    f16* lb0 = &Bs[sr][sc];      f16* lb1 = &Bs[sr + 64][sc];

    f32x4 acc[4][4] = {};
    for (int k0 = 0; k0 < CC; k0 += 32) {
        __syncthreads();
        GL16(ga0 + k0, la0);
        GL16(ga1 + k0, la1);
        GL16(gb0 + k0, lb0);
        GL16(gb1 + k0, lb1);
        __syncthreads();

        f16x8 af[4], bf[4];
        #pragma unroll
        for (int mi = 0; mi < 4; ++mi)
            af[mi] = *(const f16x8*)&As[wm + mi*16 + l15][quad * 8];
        #pragma unroll
        for (int ni = 0; ni < 4; ++ni)
            bf[ni] = *(const f16x8*)&Bs[wn + ni*16 + l15][quad * 8];
        #pragma unroll
        for (int mi = 0; mi < 4; ++mi)
            #pragma unroll
            for (int ni = 0; ni < 4; ++ni)
                acc[mi][ni] = __builtin_amdgcn_mfma_f32_16x16x32_f16(
                    af[mi], bf[ni], acc[mi][ni], 0, 0, 0);
    }

    float bb[4];
    #pragma unroll
    for (int ni = 0; ni < 4; ++ni)
        bb[ni] = bias[n0 + wn + ni*16 + l15];

    #pragma unroll
    for (int mi = 0; mi < 4; ++mi)
        #pragma unroll
        for (int r = 0; r < 4; ++r) {
            const int m = m0 + wm + mi*16 + quad*4 + r;
            #pragma unroll
            for (int ni = 0; ni < 4; ++ni)
                out[(size_t)m * CC + n0 + wn + ni*16 + l15] = acc[mi][ni][r] + bb[ni];
        }
}

// ---------------------------------------------------------------------------
extern "C" void kernel_launch(void* const* d_in, const int* in_sizes, int n_in,
                              void* d_out, int out_size, void* d_ws, size_t ws_size,
                              hipStream_t stream)
{
    const float* x     = (const float*)d_in[0];
    const float* mask  = (const float*)d_in[1];
    const float* times = (const float*)d_in[2];
    const float* Wqkv  = (const float*)d_in[3];
    const float* Wproj = (const float*)d_in[4];
    const float* bproj = (const float*)d_in[5];
    const int*   ncls  = (const int*)d_in[6];
    float* out = (float*)d_out;

    const size_t per = (size_t)BB * HH * NN * DH;   // 4,194,304 elements
    f16* xh  = (f16*)d_ws;                          // [8192][512]
    f16* wqh = xh + per;                            // [1536][512]
    f16* wph = wqh + (size_t)QKV_N * CC;            // [512][512]
    f16* q   = wph + (size_t)CC * CC;
    f16* k   = q + per;
    f16* vt  = k + per;
    f16* ao  = vt + per;                            // (B,N,C) fp16

    cast_kernel<<<(SX4 + SW4 + SP4) / 256, 256, 0, stream>>>(
        x, Wqkv, Wproj, xh, wqh, wph);
    qkv_gemm<<<dim3(MM / 128, QKV_N / 128), 256, 0, stream>>>(
        xh, wqh, q, k, vt);
    rope_kernel<<<(MM * HH * DH / 8) / 256, 256, 0, stream>>>(
        q, k, times, ncls);
    attn_kernel<<<dim3(BB * HH, NN / 128), 512, 0, stream>>>(
        q, k, vt, mask, ao);
    proj_gemm<<<dim3(MM / 128, CC / 128), 256, 0, stream>>>(
        ao, wph, bproj, out);
}

// Round 5
// 221.084 us; speedup vs baseline: 1.6691x; 1.6691x over previous
//
#include <hip/hip_runtime.h>
#include <math.h>

// Problem constants (setup_inputs): B=4, N=2048, C=512, H=8, Dh=64
#define BB 4
#define NN 2048
#define CC 512
#define HH 8
#define DH 64
#define MM (BB*NN)          // 8192 rows
#define QKV_N (3*CC)        // 1536

typedef _Float16 f16;
typedef __attribute__((ext_vector_type(4))) _Float16 f16x4;
typedef __attribute__((ext_vector_type(8))) _Float16 f16x8;
typedef __attribute__((ext_vector_type(4))) float f32x4;

#define L2E 1.4426950408889634f

// async global->LDS, 16B per lane. LDS dest is wave-uniform base + lane*16,
// so LDS layout MUST be exact lane-order (no padding).
#define GL16(g, l) __builtin_amdgcn_global_load_lds(                       \
    (const __attribute__((address_space(1))) void*)(g),                    \
    (__attribute__((address_space(3))) void*)(l), 16, 0, 0)

// ---------------------------------------------------------------------------
// Kernel 0: cast x, Wqkv, Wproj to fp16 (vectorized, memory-bound).
// ---------------------------------------------------------------------------
#define SX4 (MM*CC/4)          // 1048576
#define SW4 (QKV_N*CC/4)       // 196608
#define SP4 (CC*CC/4)          // 65536
__global__ __launch_bounds__(256) void cast_kernel(
    const float* __restrict__ x, const float* __restrict__ wqkv,
    const float* __restrict__ wproj,
    f16* __restrict__ xh, f16* __restrict__ wqh, f16* __restrict__ wph)
{
    const int t = blockIdx.x * 256 + threadIdx.x;
    const float* src; f16* dst; int i;
    if (t < SX4)            { src = x;     dst = xh;  i = t; }
    else if (t < SX4 + SW4) { src = wqkv;  dst = wqh; i = t - SX4; }
    else                    { src = wproj; dst = wph; i = t - SX4 - SW4; }
    f32x4 v = *(const f32x4*)(src + 4 * (size_t)i);
    f16x4 h = { (f16)v[0], (f16)v[1], (f16)v[2], (f16)v[3] };
    *(f16x4*)(dst + 4 * (size_t)i) = h;
}

// ---------------------------------------------------------------------------
// Kernel 1: QKV GEMM, fp16 MFMA. M=8192, N=1536, K=512. 128x128 tile, BK=32.
// Epilogue: q,k -> (B,H,N,Dh) fp16 ; v -> transposed (B,H,Dh,N) fp16.
// ---------------------------------------------------------------------------
__global__ __launch_bounds__(256) void qkv_gemm(
    const f16* __restrict__ xh, const f16* __restrict__ wh,
    f16* __restrict__ qo, f16* __restrict__ ko, f16* __restrict__ vto)
{
    __shared__ f16 As[128][32];
    __shared__ f16 Bs[128][32];
    const int m0 = blockIdx.x * 128;
    const int n0 = blockIdx.y * 128;
    const int tid = threadIdx.x;
    const int lane = tid & 63;
    const int w = tid >> 6;
    const int wm = (w & 1) * 64, wn = (w >> 1) * 64;
    const int l15 = lane & 15, quad = lane >> 4;

    const int sr = tid >> 2;           // staging row 0..63
    const int sc = (tid & 3) * 8;      // staging col (halves)
    const f16* ga0 = xh + (size_t)(m0 + sr) * CC + sc;
    const f16* ga1 = xh + (size_t)(m0 + sr + 64) * CC + sc;
    const f16* gb0 = wh + (size_t)(n0 + sr) * CC + sc;
    const f16* gb1 = wh + (size_t)(n0 + sr + 64) * CC + sc;
    f16* la0 = &As[sr][sc];      f16* la1 = &As[sr + 64][sc];
    f16* lb0 = &Bs[sr][sc];      f16* lb1 = &Bs[sr + 64][sc];

    f32x4 acc[4][4] = {};
    for (int k0 = 0; k0 < CC; k0 += 32) {
        __syncthreads();
        GL16(ga0 + k0, la0);
        GL16(ga1 + k0, la1);
        GL16(gb0 + k0, lb0);
        GL16(gb1 + k0, lb1);
        __syncthreads();

        f16x8 af[4], bf[4];
        #pragma unroll
        for (int mi = 0; mi < 4; ++mi)
            af[mi] = *(const f16x8*)&As[wm + mi*16 + l15][quad * 8];
        #pragma unroll
        for (int ni = 0; ni < 4; ++ni)
            bf[ni] = *(const f16x8*)&Bs[wn + ni*16 + l15][quad * 8];
        #pragma unroll
        for (int mi = 0; mi < 4; ++mi)
            #pragma unroll
            for (int ni = 0; ni < 4; ++ni)
                acc[mi][ni] = __builtin_amdgcn_mfma_f32_16x16x32_f16(
                    af[mi], bf[ni], acc[mi][ni], 0, 0, 0);
    }

    const int which = n0 >> 9;          // 0=q, 1=k, 2=v
    const int b     = m0 >> 11;
    const int mloc  = m0 & (NN - 1);

    if (which == 2) {
        #pragma unroll
        for (int mi = 0; mi < 4; ++mi)
            #pragma unroll
            for (int ni = 0; ni < 4; ++ni) {
                const int cl = wn + ni*16 + l15;
                const int hh = ((n0 & 511) + cl) >> 6;
                const int d  = ((n0 & 511) + cl) & 63;
                const int n  = mloc + wm + mi*16 + quad*4;
                f16x4 pk = { (f16)acc[mi][ni][0], (f16)acc[mi][ni][1],
                             (f16)acc[mi][ni][2], (f16)acc[mi][ni][3] };
                *(f16x4*)(vto + ((size_t)(b*HH + hh) * DH + d) * NN + n) = pk;
            }
        return;
    }

    f16* dst = which ? ko : qo;
    #pragma unroll
    for (int mi = 0; mi < 4; ++mi)
        #pragma unroll
        for (int r = 0; r < 4; ++r) {
            const int n = mloc + wm + mi*16 + quad*4 + r;
            #pragma unroll
            for (int ni = 0; ni < 4; ++ni) {
                const int cl = wn + ni*16 + l15;
                const int hh = ((n0 & 511) + cl) >> 6;
                const int d  = ((n0 & 511) + cl) & 63;
                dst[((size_t)(b*HH + hh) * NN + n) * DH + d] = (f16)acc[mi][ni][r];
            }
        }
}

// ---------------------------------------------------------------------------
// Kernel 2: RoPE over q,k in place (B,H,N,Dh). Fully in-lane.
// ---------------------------------------------------------------------------
__global__ __launch_bounds__(256) void rope_kernel(
    f16* __restrict__ q, f16* __restrict__ k,
    const float* __restrict__ times, const int* __restrict__ nclsp)
{
    const int t = blockIdx.x * 256 + threadIdx.x;    // 0 .. 524287
    const int row = t >> 3;                          // bh*2048 + n
    const int d0  = (t & 7) * 8;
    const int n   = row & (NN - 1);
    const int b   = row >> 14;                       // /(H*N)
    if (n < *nclsp) return;
    const float pos = rintf(times[b * NN + n] * 30.0f);   // MAX_FPS

    f16x8 qv = *(const f16x8*)(q + (size_t)row * DH + d0);
    f16x8 kv = *(const f16x8*)(k + (size_t)row * DH + d0);
    f16x8 qr, kr;
    #pragma unroll
    for (int p = 0; p < 4; ++p) {
        const int j = (d0 >> 1) + p;
        const float invf = exp2f((float)j * (-13.287712379549449f / 32.0f));
        float s, c;
        sincosf(pos * invf, &s, &c);
        const float q0 = (float)qv[2*p], q1 = (float)qv[2*p+1];
        qr[2*p]   = (f16)(q0 * c - q1 * s);
        qr[2*p+1] = (f16)(q0 * s + q1 * c);
        const float k0 = (float)kv[2*p], k1 = (float)kv[2*p+1];
        kr[2*p]   = (f16)(k0 * c - k1 * s);
        kr[2*p+1] = (f16)(k0 * s + k1 * c);
    }
    *(f16x8*)(q + (size_t)row * DH + d0) = qr;
    *(f16x8*)(k + (size_t)row * DH + d0) = kr;
}

// ---------------------------------------------------------------------------
// Kernel 3: fp16-MFMA flash attention, register-resident P.
// Grid (32 bh, 32 qt); block 256 = 4 waves; wave owns 16 q rows.
// S^T = K·Q^T via 16x16x32 (C-frag: col=q=l15, row=key=quad*4+r).
// KEY TRICK: that C-frag IS the B-operand layout of v_mfma_f32_16x16x16f16,
// so O^T = V^T·P^T accumulates with P taken straight from registers —
// no LDS round-trip, and q=l15 in-lane => alpha/l are scalar per lane.
// Pads: 66 halves = 33 dwords == 1 mod 32 => <=2-way bank aliasing (free).
// ---------------------------------------------------------------------------
__global__ __launch_bounds__(256, 4) void attn_kernel(
    const f16* __restrict__ qg, const f16* __restrict__ kg,
    const f16* __restrict__ vtg, const float* __restrict__ mask,
    f16* __restrict__ out)
{
    __shared__ f16 Kh[64][66];     // [key][d]
    __shared__ f16 Vt[64][66];     // [d][key]
    __shared__ float Msk[64];      // mask*log2e for current key tile

    const int bh = blockIdx.x;           // 0..31
    const int qt = blockIdx.y;           // 0..31 (64-row q tiles)
    const int b = bh >> 3, h = bh & 7;
    const int tid = threadIdx.x;
    const int w = tid >> 6, lane = tid & 63;
    const int l15 = lane & 15, quad = lane >> 4;

    const f16* qbase  = qg  + ((size_t)bh * NN + qt*64 + w*16) * DH;
    const f16* kbase  = kg  + (size_t)bh * NN * DH;
    const f16* vtbase = vtg + (size_t)bh * DH * NN;
    const float* mbase = mask + (size_t)b * NN;

    // Q B-fragments (persistent): q = l15, d = kc*32 + quad*8 .. +8
    f16x8 Bq[2];
    #pragma unroll
    for (int kc = 0; kc < 2; ++kc)
        Bq[kc] = *(const f16x8*)(qbase + (size_t)l15 * DH + kc*32 + quad*8);

    // O^T accumulators: col q = l15 (in-lane!), row d = 16*nd + quad*4 + r
    f32x4 O[4] = {};
    float m_run = -INFINITY, l_run = 0.0f;
    const float scl = 0.125f * L2E;

    const int sr = tid >> 3;             // 0..31
    const int scol = (tid & 7) * 8;

    for (int kt = 0; kt < 32; ++kt) {
        __syncthreads();                 // prior-iter tile reads done
        *(f16x8*)&Kh[sr][scol] =
            *(const f16x8*)(kbase + (size_t)(kt*64 + sr) * DH + scol);
        *(f16x8*)&Kh[sr+32][scol] =
            *(const f16x8*)(kbase + (size_t)(kt*64 + sr + 32) * DH + scol);
        *(f16x8*)&Vt[sr][scol] =
            *(const f16x8*)(vtbase + (size_t)sr * NN + kt*64 + scol);
        *(f16x8*)&Vt[sr+32][scol] =
            *(const f16x8*)(vtbase + (size_t)(sr + 32) * NN + kt*64 + scol);
        if (tid < 16) {
            f32x4 mv = *(const f32x4*)(mbase + kt*64 + (tid << 2));
            mv *= L2E;
            *(f32x4*)&Msk[tid << 2] = mv;
        }
        __syncthreads();

        // S^T = K · Q^T  (M=key, N=q): st[mi] covers keys 16mi..16mi+15
        f32x4 st[4] = {};
        #pragma unroll
        for (int mi = 0; mi < 4; ++mi) {
            f16x8 Ak0 = *(const f16x8*)&Kh[16*mi + l15][quad*8];
            f16x8 Ak1 = *(const f16x8*)&Kh[16*mi + l15][32 + quad*8];
            st[mi] = __builtin_amdgcn_mfma_f32_16x16x32_f16(Ak0, Bq[0], st[mi], 0, 0, 0);
            st[mi] = __builtin_amdgcn_mfma_f32_16x16x32_f16(Ak1, Bq[1], st[mi], 0, 0, 0);
        }

        // scale + mask (exp2 domain); in-lane max over 16 keys, then quads
        float mloc = -INFINITY;
        #pragma unroll
        for (int mi = 0; mi < 4; ++mi) {
            f32x4 mk = *(const f32x4*)&Msk[16*mi + quad*4];
            #pragma unroll
            for (int r = 0; r < 4; ++r) {
                float s2 = st[mi][r] * scl + mk[r];
                st[mi][r] = s2;
                mloc = fmaxf(mloc, s2);
            }
        }
        mloc = fmaxf(mloc, __shfl_xor(mloc, 16));
        mloc = fmaxf(mloc, __shfl_xor(mloc, 32));
        const float mnew = fmaxf(m_run, mloc);
        const float alpha = exp2f(m_run - mnew);
        m_run = mnew;

        float rs = 0.0f;
        f16x4 ph[4];
        #pragma unroll
        for (int mi = 0; mi < 4; ++mi)
            #pragma unroll
            for (int r = 0; r < 4; ++r) {
                float p = exp2f(st[mi][r] - mnew);
                rs += p;
                ph[mi][r] = (f16)p;
            }
        rs += __shfl_xor(rs, 16);
        rs += __shfl_xor(rs, 32);
        l_run = l_run * alpha + rs;

        #pragma unroll
        for (int nd = 0; nd < 4; ++nd)
            O[nd] *= alpha;

        // O^T += V^T · P^T : A = Vt b64 frags, B = ph[mi] DIRECT (no LDS!)
        #pragma unroll
        for (int mi = 0; mi < 4; ++mi) {
            #pragma unroll
            for (int nd = 0; nd < 4; ++nd) {
                f16x4 Av = *(const f16x4*)&Vt[16*nd + l15][16*mi + quad*4];
                O[nd] = __builtin_amdgcn_mfma_f32_16x16x16f16(Av, ph[mi], O[nd], 0, 0, 0);
            }
        }
    }

    // Normalize (in-lane) and write (B, N, C): q = l15, d = 16nd+quad*4+r
    const float inv = 1.0f / l_run;
    const int qrow = qt*64 + w*16 + l15;
    f16* obase = out + ((size_t)b * NN + qrow) * CC + h * DH;
    #pragma unroll
    for (int nd = 0; nd < 4; ++nd) {
        f32x4 o = O[nd] * inv;
        f16x4 oh = { (f16)o[0], (f16)o[1], (f16)o[2], (f16)o[3] };
        *(f16x4*)(obase + 16*nd + quad*4) = oh;
    }
}

// ---------------------------------------------------------------------------
// Kernel 4: proj GEMM, fp16 MFMA. M=8192, N=512, K=512. fp32 out + bias.
// ---------------------------------------------------------------------------
__global__ __launch_bounds__(256) void proj_gemm(
    const f16* __restrict__ ah, const f16* __restrict__ wh,
    const float* __restrict__ bias, float* __restrict__ out)
{
    __shared__ f16 As[128][32];
    __shared__ f16 Bs[128][32];
    const int m0 = blockIdx.x * 128;
    const int n0 = blockIdx.y * 128;
    const int tid = threadIdx.x;
    const int lane = tid & 63;
    const int w = tid >> 6;
    const int wm = (w & 1) * 64, wn = (w >> 1) * 64;
    const int l15 = lane & 15, quad = lane >> 4;

    const int sr = tid >> 2;
    const int sc = (tid & 3) * 8;
    const f16* ga0 = ah + (size_t)(m0 + sr) * CC + sc;
    const f16* ga1 = ah + (size_t)(m0 + sr + 64) * CC + sc;
    const f16* gb0 = wh + (size_t)(n0 + sr) * CC + sc;
    const f16* gb1 = wh + (size_t)(n0 + sr + 64) * CC + sc;
    f16* la0 = &As[sr][sc];      f16* la1 = &As[sr + 64][sc];
    f16* lb0 = &Bs[sr][sc];      f16* lb1 = &Bs[sr + 64][sc];

    f32x4 acc[4][4] = {};
    for (int k0 = 0; k0 < CC; k0 += 32) {
        __syncthreads();
        GL16(ga0 + k0, la0);
        GL16(ga1 + k0, la1);
        GL16(gb0 + k0, lb0);
        GL16(gb1 + k0, lb1);
        __syncthreads();

        f16x8 af[4], bf[4];
        #pragma unroll
        for (int mi = 0; mi < 4; ++mi)
            af[mi] = *(const f16x8*)&As[wm + mi*16 + l15][quad * 8];
        #pragma unroll
        for (int ni = 0; ni < 4; ++ni)
            bf[ni] = *(const f16x8*)&Bs[wn + ni*16 + l15][quad * 8];
        #pragma unroll
        for (int mi = 0; mi < 4; ++mi)
            #pragma unroll
            for (int ni = 0; ni < 4; ++ni)
                acc[mi][ni] = __builtin_amdgcn_mfma_f32_16x16x32_f16(
                    af[mi], bf[ni], acc[mi][ni], 0, 0, 0);
    }

    float bb[4];
    #pragma unroll
    for (int ni = 0; ni < 4; ++ni)
        bb[ni] = bias[n0 + wn + ni*16 + l15];

    #pragma unroll
    for (int mi = 0; mi < 4; ++mi)
        #pragma unroll
        for (int r = 0; r < 4; ++r) {
            const int m = m0 + wm + mi*16 + quad*4 + r;
            #pragma unroll
            for (int ni = 0; ni < 4; ++ni)
                out[(size_t)m * CC + n0 + wn + ni*16 + l15] = acc[mi][ni][r] + bb[ni];
        }
}

// ---------------------------------------------------------------------------
extern "C" void kernel_launch(void* const* d_in, const int* in_sizes, int n_in,
                              void* d_out, int out_size, void* d_ws, size_t ws_size,
                              hipStream_t stream)
{
    const float* x     = (const float*)d_in[0];
    const float* mask  = (const float*)d_in[1];
    const float* times = (const float*)d_in[2];
    const float* Wqkv  = (const float*)d_in[3];
    const float* Wproj = (const float*)d_in[4];
    const float* bproj = (const float*)d_in[5];
    const int*   ncls  = (const int*)d_in[6];
    float* out = (float*)d_out;

    const size_t per = (size_t)BB * HH * NN * DH;   // 4,194,304 elements
    f16* xh  = (f16*)d_ws;                          // [8192][512]
    f16* wqh = xh + per;                            // [1536][512]
    f16* wph = wqh + (size_t)QKV_N * CC;            // [512][512]
    f16* q   = wph + (size_t)CC * CC;
    f16* k   = q + per;
    f16* vt  = k + per;
    f16* ao  = vt + per;                            // (B,N,C) fp16

    cast_kernel<<<(SX4 + SW4 + SP4) / 256, 256, 0, stream>>>(
        x, Wqkv, Wproj, xh, wqh, wph);
    qkv_gemm<<<dim3(MM / 128, QKV_N / 128), 256, 0, stream>>>(
        xh, wqh, q, k, vt);
    rope_kernel<<<(MM * HH * DH / 8) / 256, 256, 0, stream>>>(
        q, k, times, ncls);
    attn_kernel<<<dim3(BB * HH, NN / 64), 256, 0, stream>>>(
        q, k, vt, mask, ao);
    proj_gemm<<<dim3(MM / 128, CC / 128), 256, 0, stream>>>(
        ao, wph, bproj, out);
}

// Round 6
// 198.792 us; speedup vs baseline: 1.8562x; 1.1121x over previous
//
#include <hip/hip_runtime.h>
#include <math.h>

// Problem constants (setup_inputs): B=4, N=2048, C=512, H=8, Dh=64
#define BB 4
#define NN 2048
#define CC 512
#define HH 8
#define DH 64
#define MM (BB*NN)          // 8192 rows
#define QKV_N (3*CC)        // 1536

typedef _Float16 f16;
typedef __attribute__((ext_vector_type(4))) _Float16 f16x4;
typedef __attribute__((ext_vector_type(8))) _Float16 f16x8;
typedef __attribute__((ext_vector_type(4))) float f32x4;

#define L2E 1.4426950408889634f

// async global->LDS, 16B per lane. LDS dest is wave-uniform base + lane*16,
// so LDS layout MUST be exact lane-order (no padding).
#define GL16(g, l) __builtin_amdgcn_global_load_lds(                       \
    (const __attribute__((address_space(1))) void*)(g),                    \
    (__attribute__((address_space(3))) void*)(l), 16, 0, 0)

// ---------------------------------------------------------------------------
// Kernel 0: cast x, Wqkv, Wproj to fp16 (vectorized, memory-bound).
// ---------------------------------------------------------------------------
#define SX4 (MM*CC/4)          // 1048576
#define SW4 (QKV_N*CC/4)       // 196608
#define SP4 (CC*CC/4)          // 65536
__global__ __launch_bounds__(256) void cast_kernel(
    const float* __restrict__ x, const float* __restrict__ wqkv,
    const float* __restrict__ wproj,
    f16* __restrict__ xh, f16* __restrict__ wqh, f16* __restrict__ wph)
{
    const int t = blockIdx.x * 256 + threadIdx.x;
    const float* src; f16* dst; int i;
    if (t < SX4)            { src = x;     dst = xh;  i = t; }
    else if (t < SX4 + SW4) { src = wqkv;  dst = wqh; i = t - SX4; }
    else                    { src = wproj; dst = wph; i = t - SX4 - SW4; }
    f32x4 v = *(const f32x4*)(src + 4 * (size_t)i);
    f16x4 h = { (f16)v[0], (f16)v[1], (f16)v[2], (f16)v[3] };
    *(f16x4*)(dst + 4 * (size_t)i) = h;
}

// ---------------------------------------------------------------------------
// Kernel 1: QKV GEMM, fp16 MFMA. M=8192, N=1536, K=512. 128x128 tile, BK=32.
// Epilogue: q,k -> (B,H,N,Dh) fp16 ; v -> transposed (B,H,Dh,N) fp16.
// ---------------------------------------------------------------------------
__global__ __launch_bounds__(256) void qkv_gemm(
    const f16* __restrict__ xh, const f16* __restrict__ wh,
    f16* __restrict__ qo, f16* __restrict__ ko, f16* __restrict__ vto)
{
    __shared__ f16 As[128][32];
    __shared__ f16 Bs[128][32];
    const int m0 = blockIdx.x * 128;
    const int n0 = blockIdx.y * 128;
    const int tid = threadIdx.x;
    const int lane = tid & 63;
    const int w = tid >> 6;
    const int wm = (w & 1) * 64, wn = (w >> 1) * 64;
    const int l15 = lane & 15, quad = lane >> 4;

    const int sr = tid >> 2;           // staging row 0..63
    const int sc = (tid & 3) * 8;      // staging col (halves)
    const f16* ga0 = xh + (size_t)(m0 + sr) * CC + sc;
    const f16* ga1 = xh + (size_t)(m0 + sr + 64) * CC + sc;
    const f16* gb0 = wh + (size_t)(n0 + sr) * CC + sc;
    const f16* gb1 = wh + (size_t)(n0 + sr + 64) * CC + sc;
    f16* la0 = &As[sr][sc];      f16* la1 = &As[sr + 64][sc];
    f16* lb0 = &Bs[sr][sc];      f16* lb1 = &Bs[sr + 64][sc];

    f32x4 acc[4][4] = {};
    for (int k0 = 0; k0 < CC; k0 += 32) {
        __syncthreads();
        GL16(ga0 + k0, la0);
        GL16(ga1 + k0, la1);
        GL16(gb0 + k0, lb0);
        GL16(gb1 + k0, lb1);
        __syncthreads();

        f16x8 af[4], bf[4];
        #pragma unroll
        for (int mi = 0; mi < 4; ++mi)
            af[mi] = *(const f16x8*)&As[wm + mi*16 + l15][quad * 8];
        #pragma unroll
        for (int ni = 0; ni < 4; ++ni)
            bf[ni] = *(const f16x8*)&Bs[wn + ni*16 + l15][quad * 8];
        #pragma unroll
        for (int mi = 0; mi < 4; ++mi)
            #pragma unroll
            for (int ni = 0; ni < 4; ++ni)
                acc[mi][ni] = __builtin_amdgcn_mfma_f32_16x16x32_f16(
                    af[mi], bf[ni], acc[mi][ni], 0, 0, 0);
    }

    const int which = n0 >> 9;          // 0=q, 1=k, 2=v
    const int b     = m0 >> 11;
    const int mloc  = m0 & (NN - 1);

    if (which == 2) {
        #pragma unroll
        for (int mi = 0; mi < 4; ++mi)
            #pragma unroll
            for (int ni = 0; ni < 4; ++ni) {
                const int cl = wn + ni*16 + l15;
                const int hh = ((n0 & 511) + cl) >> 6;
                const int d  = ((n0 & 511) + cl) & 63;
                const int n  = mloc + wm + mi*16 + quad*4;
                f16x4 pk = { (f16)acc[mi][ni][0], (f16)acc[mi][ni][1],
                             (f16)acc[mi][ni][2], (f16)acc[mi][ni][3] };
                *(f16x4*)(vto + ((size_t)(b*HH + hh) * DH + d) * NN + n) = pk;
            }
        return;
    }

    f16* dst = which ? ko : qo;
    #pragma unroll
    for (int mi = 0; mi < 4; ++mi)
        #pragma unroll
        for (int r = 0; r < 4; ++r) {
            const int n = mloc + wm + mi*16 + quad*4 + r;
            #pragma unroll
            for (int ni = 0; ni < 4; ++ni) {
                const int cl = wn + ni*16 + l15;
                const int hh = ((n0 & 511) + cl) >> 6;
                const int d  = ((n0 & 511) + cl) & 63;
                dst[((size_t)(b*HH + hh) * NN + n) * DH + d] = (f16)acc[mi][ni][r];
            }
        }
}

// ---------------------------------------------------------------------------
// Kernel 2: RoPE over q,k in place (B,H,N,Dh). Fully in-lane.
// ---------------------------------------------------------------------------
__global__ __launch_bounds__(256) void rope_kernel(
    f16* __restrict__ q, f16* __restrict__ k,
    const float* __restrict__ times, const int* __restrict__ nclsp)
{
    const int t = blockIdx.x * 256 + threadIdx.x;    // 0 .. 524287
    const int row = t >> 3;                          // bh*2048 + n
    const int d0  = (t & 7) * 8;
    const int n   = row & (NN - 1);
    const int b   = row >> 14;                       // /(H*N)
    if (n < *nclsp) return;
    const float pos = rintf(times[b * NN + n] * 30.0f);   // MAX_FPS

    f16x8 qv = *(const f16x8*)(q + (size_t)row * DH + d0);
    f16x8 kv = *(const f16x8*)(k + (size_t)row * DH + d0);
    f16x8 qr, kr;
    #pragma unroll
    for (int p = 0; p < 4; ++p) {
        const int j = (d0 >> 1) + p;
        const float invf = exp2f((float)j * (-13.287712379549449f / 32.0f));
        float s, c;
        sincosf(pos * invf, &s, &c);
        const float q0 = (float)qv[2*p], q1 = (float)qv[2*p+1];
        qr[2*p]   = (f16)(q0 * c - q1 * s);
        qr[2*p+1] = (f16)(q0 * s + q1 * c);
        const float k0 = (float)kv[2*p], k1 = (float)kv[2*p+1];
        kr[2*p]   = (f16)(k0 * c - k1 * s);
        kr[2*p+1] = (f16)(k0 * s + k1 * c);
    }
    *(f16x8*)(q + (size_t)row * DH + d0) = qr;
    *(f16x8*)(k + (size_t)row * DH + d0) = kr;
}

// ---------------------------------------------------------------------------
// Kernel 3: fp16-MFMA flash attention, register-resident P, XOR-swizzled LDS.
// Grid (32 bh, 16 qt); block 256 = 4 waves; each wave owns 32 q rows (ni=0,1).
// S^T = K·Q^T (16x16x32); P stays in registers as the B-operand of
// O^T = V^T·P^T (16x16x16). Row-sums l accumulate via a ones-A-frag MFMA
// ("row 64 of O^T") so alpha-rescale applies to l automatically.
// LDS tiles Kh[key][d], Vt[d][key] use phys_block = blk ^ (row&7) XOR
// swizzle -> staging writes, Ak b128 reads, Av b64 reads all conflict-free.
// ---------------------------------------------------------------------------
__global__ __launch_bounds__(256, 2) void attn_kernel(
    const f16* __restrict__ qg, const f16* __restrict__ kg,
    const f16* __restrict__ vtg, const float* __restrict__ mask,
    f16* __restrict__ out)
{
    __shared__ f16 Kh[64][64];     // [key][d], swizzled
    __shared__ f16 Vt[64][64];     // [d][key], swizzled
    __shared__ float Msk[64];      // mask*log2e for current key tile

    const int bh = blockIdx.x;           // 0..31
    const int qt = blockIdx.y;           // 0..15 (128-row q tiles)
    const int b = bh >> 3, h = bh & 7;
    const int tid = threadIdx.x;
    const int w = tid >> 6, lane = tid & 63;
    const int l15 = lane & 15, quad = lane >> 4;
    const int rho = l15 & 7;

    const f16* qbase  = qg  + ((size_t)bh * NN + qt*128 + w*32) * DH;
    const f16* kbase  = kg  + (size_t)bh * NN * DH;
    const f16* vtbase = vtg + (size_t)bh * DH * NN;
    const float* mbase = mask + (size_t)b * NN;

    // Q B-fragments (persistent): q = 16ni + l15, d = kc*32 + quad*8 .. +8
    f16x8 Bq[2][2];
    #pragma unroll
    for (int ni = 0; ni < 2; ++ni)
        #pragma unroll
        for (int kc = 0; kc < 2; ++kc)
            Bq[ni][kc] = *(const f16x8*)(qbase + (size_t)(16*ni + l15) * DH
                                         + kc*32 + quad*8);

    // Ones A-frag for l accumulation: A[m=l15][k=quad*4+i] = (m==0)
    const f16x4 Aones = (l15 == 0) ? f16x4{1.0f16, 1.0f16, 1.0f16, 1.0f16}
                                   : f16x4{0.0f16, 0.0f16, 0.0f16, 0.0f16};

    // O^T accumulators: col q = l15 (in-lane), row d = 16*nd + quad*4 + r
    f32x4 O[2][4] = {};
    f32x4 Lacc[2] = {};                  // "row 64": row sums (l) per q
    float m_run[2] = { -INFINITY, -INFINITY };
    const float scl = 0.125f * L2E;

    // staging geometry: row srr/srr+32, 16B block scb; swizzled col sw
    const int srr = tid >> 3;            // 0..31
    const int scb = tid & 7;             // 0..7
    const int sw  = (scb ^ (srr & 7)) * 8;   // (srr+32)&7 == srr&7

    for (int kt = 0; kt < 32; ++kt) {
        __syncthreads();                 // prior-iter tile reads done
        f16x8 k0 = *(const f16x8*)(kbase + (size_t)(kt*64 + srr) * DH + scb*8);
        f16x8 k1 = *(const f16x8*)(kbase + (size_t)(kt*64 + srr + 32) * DH + scb*8);
        f16x8 v0 = *(const f16x8*)(vtbase + (size_t)srr * NN + kt*64 + scb*8);
        f16x8 v1 = *(const f16x8*)(vtbase + (size_t)(srr + 32) * NN + kt*64 + scb*8);
        *(f16x8*)&Kh[srr][sw]      = k0;
        *(f16x8*)&Kh[srr + 32][sw] = k1;
        *(f16x8*)&Vt[srr][sw]      = v0;
        *(f16x8*)&Vt[srr + 32][sw] = v1;
        if (tid < 16) {
            f32x4 mv = *(const f32x4*)(mbase + kt*64 + (tid << 2));
            mv *= L2E;
            *(f32x4*)&Msk[tid << 2] = mv;
        }
        __syncthreads();

        // S^T = K · Q^T : st[mi][ni], keys 16mi+quad*4+r, q = 16ni+l15
        f32x4 st[4][2] = {};
        const int aw = (quad ^ rho) * 8;
        #pragma unroll
        for (int mi = 0; mi < 4; ++mi) {
            f16x8 Ak0 = *(const f16x8*)&Kh[16*mi + l15][aw];
            f16x8 Ak1 = *(const f16x8*)&Kh[16*mi + l15][aw ^ 32];
            #pragma unroll
            for (int ni = 0; ni < 2; ++ni) {
                st[mi][ni] = __builtin_amdgcn_mfma_f32_16x16x32_f16(Ak0, Bq[ni][0], st[mi][ni], 0, 0, 0);
                st[mi][ni] = __builtin_amdgcn_mfma_f32_16x16x32_f16(Ak1, Bq[ni][1], st[mi][ni], 0, 0, 0);
            }
        }

        f32x4 mskv[4];
        #pragma unroll
        for (int mi = 0; mi < 4; ++mi)
            mskv[mi] = *(const f32x4*)&Msk[16*mi + quad*4];

        f16x4 ph[4][2];
        float alpha[2];
        #pragma unroll
        for (int ni = 0; ni < 2; ++ni) {
            float mloc = -INFINITY;
            #pragma unroll
            for (int mi = 0; mi < 4; ++mi)
                #pragma unroll
                for (int r = 0; r < 4; ++r) {
                    float s2 = st[mi][ni][r] * scl + mskv[mi][r];
                    st[mi][ni][r] = s2;
                    mloc = fmaxf(mloc, s2);
                }
            mloc = fmaxf(mloc, __shfl_xor(mloc, 16));
            mloc = fmaxf(mloc, __shfl_xor(mloc, 32));
            const float mnew = fmaxf(m_run[ni], mloc);
            alpha[ni] = exp2f(m_run[ni] - mnew);
            m_run[ni] = mnew;
            #pragma unroll
            for (int mi = 0; mi < 4; ++mi)
                #pragma unroll
                for (int r = 0; r < 4; ++r)
                    ph[mi][ni][r] = (f16)exp2f(st[mi][ni][r] - mnew);
            // rescale O and L (L rides along -> no separate l bookkeeping)
            #pragma unroll
            for (int nd = 0; nd < 4; ++nd)
                O[ni][nd] *= alpha[ni];
            Lacc[ni] *= alpha[ni];
        }

        // O^T += V^T · P^T ; L += 1^T · P^T   (P direct from registers)
        #pragma unroll
        for (int mi = 0; mi < 4; ++mi) {
            Lacc[0] = __builtin_amdgcn_mfma_f32_16x16x16f16(Aones, ph[mi][0], Lacc[0], 0, 0, 0);
            Lacc[1] = __builtin_amdgcn_mfma_f32_16x16x16f16(Aones, ph[mi][1], Lacc[1], 0, 0, 0);
            #pragma unroll
            for (int nd = 0; nd < 4; ++nd) {
                const int vb = ((2*mi + (quad >> 1)) ^ rho) * 8 + (quad & 1) * 4;
                f16x4 Av = *(const f16x4*)&Vt[16*nd + l15][vb];
                O[0][nd] = __builtin_amdgcn_mfma_f32_16x16x16f16(Av, ph[mi][0], O[0][nd], 0, 0, 0);
                O[1][nd] = __builtin_amdgcn_mfma_f32_16x16x16f16(Av, ph[mi][1], O[1][nd], 0, 0, 0);
            }
        }
    }

    // l lives in Lacc[ni][0] of quad-0 lanes (C row 0) -> fetch per q=l15.
    #pragma unroll
    for (int ni = 0; ni < 2; ++ni) {
        const float l = __shfl(Lacc[ni][0], l15);
        const float inv = 1.0f / l;
        const int qrow = qt*128 + w*32 + 16*ni + l15;
        f16* obase = out + ((size_t)b * NN + qrow) * CC + h * DH;
        #pragma unroll
        for (int nd = 0; nd < 4; ++nd) {
            f32x4 o = O[ni][nd] * inv;
            f16x4 oh = { (f16)o[0], (f16)o[1], (f16)o[2], (f16)o[3] };
            *(f16x4*)(obase + 16*nd + quad*4) = oh;
        }
    }
}

// ---------------------------------------------------------------------------
// Kernel 4: proj GEMM, fp16 MFMA. M=8192, N=512, K=512. fp32 out + bias.
// ---------------------------------------------------------------------------
__global__ __launch_bounds__(256) void proj_gemm(
    const f16* __restrict__ ah, const f16* __restrict__ wh,
    const float* __restrict__ bias, float* __restrict__ out)
{
    __shared__ f16 As[128][32];
    __shared__ f16 Bs[128][32];
    const int m0 = blockIdx.x * 128;
    const int n0 = blockIdx.y * 128;
    const int tid = threadIdx.x;
    const int lane = tid & 63;
    const int w = tid >> 6;
    const int wm = (w & 1) * 64, wn = (w >> 1) * 64;
    const int l15 = lane & 15, quad = lane >> 4;

    const int sr = tid >> 2;
    const int sc = (tid & 3) * 8;
    const f16* ga0 = ah + (size_t)(m0 + sr) * CC + sc;
    const f16* ga1 = ah + (size_t)(m0 + sr + 64) * CC + sc;
    const f16* gb0 = wh + (size_t)(n0 + sr) * CC + sc;
    const f16* gb1 = wh + (size_t)(n0 + sr + 64) * CC + sc;
    f16* la0 = &As[sr][sc];      f16* la1 = &As[sr + 64][sc];
    f16* lb0 = &Bs[sr][sc];      f16* lb1 = &Bs[sr + 64][sc];

    f32x4 acc[4][4] = {};
    for (int k0 = 0; k0 < CC; k0 += 32) {
        __syncthreads();
        GL16(ga0 + k0, la0);
        GL16(ga1 + k0, la1);
        GL16(gb0 + k0, lb0);
        GL16(gb1 + k0, lb1);
        __syncthreads();

        f16x8 af[4], bf[4];
        #pragma unroll
        for (int mi = 0; mi < 4; ++mi)
            af[mi] = *(const f16x8*)&As[wm + mi*16 + l15][quad * 8];
        #pragma unroll
        for (int ni = 0; ni < 4; ++ni)
            bf[ni] = *(const f16x8*)&Bs[wn + ni*16 + l15][quad * 8];
        #pragma unroll
        for (int mi = 0; mi < 4; ++mi)
            #pragma unroll
            for (int ni = 0; ni < 4; ++ni)
                acc[mi][ni] = __builtin_amdgcn_mfma_f32_16x16x32_f16(
                    af[mi], bf[ni], acc[mi][ni], 0, 0, 0);
    }

    float bb[4];
    #pragma unroll
    for (int ni = 0; ni < 4; ++ni)
        bb[ni] = bias[n0 + wn + ni*16 + l15];

    #pragma unroll
    for (int mi = 0; mi < 4; ++mi)
        #pragma unroll
        for (int r = 0; r < 4; ++r) {
            const int m = m0 + wm + mi*16 + quad*4 + r;
            #pragma unroll
            for (int ni = 0; ni < 4; ++ni)
                out[(size_t)m * CC + n0 + wn + ni*16 + l15] = acc[mi][ni][r] + bb[ni];
        }
}

// ---------------------------------------------------------------------------
extern "C" void kernel_launch(void* const* d_in, const int* in_sizes, int n_in,
                              void* d_out, int out_size, void* d_ws, size_t ws_size,
                              hipStream_t stream)
{
    const float* x     = (const float*)d_in[0];
    const float* mask  = (const float*)d_in[1];
    const float* times = (const float*)d_in[2];
    const float* Wqkv  = (const float*)d_in[3];
    const float* Wproj = (const float*)d_in[4];
    const float* bproj = (const float*)d_in[5];
    const int*   ncls  = (const int*)d_in[6];
    float* out = (float*)d_out;

    const size_t per = (size_t)BB * HH * NN * DH;   // 4,194,304 elements
    f16* xh  = (f16*)d_ws;                          // [8192][512]
    f16* wqh = xh + per;                            // [1536][512]
    f16* wph = wqh + (size_t)QKV_N * CC;            // [512][512]
    f16* q   = wph + (size_t)CC * CC;
    f16* k   = q + per;
    f16* vt  = k + per;
    f16* ao  = vt + per;                            // (B,N,C) fp16

    cast_kernel<<<(SX4 + SW4 + SP4) / 256, 256, 0, stream>>>(
        x, Wqkv, Wproj, xh, wqh, wph);
    qkv_gemm<<<dim3(MM / 128, QKV_N / 128), 256, 0, stream>>>(
        xh, wqh, q, k, vt);
    rope_kernel<<<(MM * HH * DH / 8) / 256, 256, 0, stream>>>(
        q, k, times, ncls);
    attn_kernel<<<dim3(BB * HH, NN / 128), 256, 0, stream>>>(
        q, k, vt, mask, ao);
    proj_gemm<<<dim3(MM / 128, CC / 128), 256, 0, stream>>>(
        ao, wph, bproj, out);
}